// Round 1
// baseline (701.432 us; speedup 1.0000x reference)
//
#include <hip/hip_runtime.h>
#include <math.h>

#define NA 16
#define NS 64
#define NB 100
#define NE 12
#define ML 20
#define DD 512
#define NC (NA*NE)   /* 192 */
#define NR (NA*NS)   /* 1024 */
#define EPSF 1e-5f
#define DELTA_F 0.2f
#define PIT 36       /* LDS tile pitch in floats: %4==0 for float4 reads, pad-4 for bank spread */

// active-column list: g_cols[0]=count, g_cols[1..NC]=col indices (padded by replicating last)
__device__ int g_cols[1 + NC];

// ---------- helpers ----------
__device__ inline void wave_minmax64(float v, float& mn, float& mx){
  mn = v; mx = v;
  #pragma unroll
  for (int off = 32; off > 0; off >>= 1){
    mn = fminf(mn, __shfl_xor(mn, off));
    mx = fmaxf(mx, __shfl_xor(mx, off));
  }
}

__device__ inline float block_sum256(float v, float* sred){
  int t = threadIdx.x;
  #pragma unroll
  for (int off = 32; off > 0; off >>= 1) v += __shfl_xor(v, off);
  if ((t & 63) == 0) sred[t >> 6] = v;
  __syncthreads();
  float tot = sred[0] + sred[1] + sred[2] + sred[3];
  __syncthreads();
  return tot;
}

// ---------- K0: build active column list (grid-uniform, depends only on elen) ----------
__global__ void k_cols(const int* __restrict__ elen)
{
  if (blockIdx.x == 0 && threadIdx.x == 0){
    int n = 0;
    for (int aw = 0; aw < NA; ++aw){
      int L = elen[aw];
      if (L < 0) L = 0; if (L > NE) L = NE;
      for (int e = 0; e < L; ++e) g_cols[1 + n++] = aw * NE + e;
    }
    g_cols[0] = n;
    int last = (n > 0) ? g_cols[n] : 0;
    for (int i = n; i < NC; ++i) g_cols[1 + i] = last;
  }
}

// ---------- K1: fused GEMM + max/argmax over Nb, active columns only ----------
// one block per r = a*NS+s. K-loop templated on JC (number of 16-col groups this pass).
// Each surviving dot keeps the exact sequential-k fmaf chain of the previous kernel
// (k0 chunks ascending, kk ascending) -> bitwise-identical D_sim/D_ind.
template<int JC>
__device__ __forceinline__ void gemm_pass(
    const float* __restrict__ abase, const float* __restrict__ word,
    const int* __restrict__ scols, float* __restrict__ As, float* __restrict__ Bs,
    int t, int tc, int tb)
{
  float acc[7][JC];
  #pragma unroll
  for (int j = 0; j < 7; ++j)
    #pragma unroll
    for (int jc = 0; jc < JC; ++jc) acc[j][jc] = 0.f;

  for (int k0 = 0; k0 < DD; k0 += 32){
    // stage A: 100 rows x 32, pitch 36 (16B-aligned float4 stores)
    for (int i = t; i < NB * 8; i += 256){
      int b = i >> 3, q = i & 7;
      *(float4*)&As[b * PIT + q * 4] = *(const float4*)(abase + (size_t)b * DD + k0 + q * 4);
    }
    // stage B: only the JC*16 active columns of this pass
    for (int i = t; i < JC * 16 * 8; i += 256){
      int c = i >> 3, q = i & 7;
      *(float4*)&Bs[c * PIT + q * 4] = *(const float4*)(word + (size_t)scols[c] * DD + k0 + q * 4);
    }
    __syncthreads();
    #pragma unroll
    for (int kk = 0; kk < 32; kk += 4){
      float4 breg[JC];
      float4 areg[7];
      #pragma unroll
      for (int jc = 0; jc < JC; ++jc)
        breg[jc] = *(const float4*)&Bs[(jc * 16 + tc) * PIT + kk];
      #pragma unroll
      for (int j = 0; j < 7; ++j){
        int b = tb * 7 + j; b = (b < NB) ? b : (NB - 1);
        areg[j] = *(const float4*)&As[b * PIT + kk];
      }
      #pragma unroll
      for (int j = 0; j < 7; ++j)
        #pragma unroll
        for (int jc = 0; jc < JC; ++jc){
          float s0 = acc[j][jc];
          s0 = fmaf(areg[j].x, breg[jc].x, s0);
          s0 = fmaf(areg[j].y, breg[jc].y, s0);
          s0 = fmaf(areg[j].z, breg[jc].z, s0);
          s0 = fmaf(areg[j].w, breg[jc].w, s0);
          acc[j][jc] = s0;
        }
    }
    __syncthreads();
  }
  // per-thread max/argmax over this thread's rows; redv aliases As, redi aliases Bs
  #pragma unroll
  for (int jc = 0; jc < JC; ++jc){
    int ci = jc * 16 + tc;
    float best = -3.4e38f; int bi = 0;
    #pragma unroll
    for (int j = 0; j < 7; ++j){
      int b = tb * 7 + j;
      if (b < NB){ float v = acc[j][jc]; if (v > best){ best = v; bi = b; } }
    }
    As[ci * 16 + tb] = best;
    Bs[ci * 16 + tb] = (float)bi;
  }
}

__device__ __forceinline__ void gemm_epilogue(
    const float* __restrict__ As, const float* __restrict__ Bs,
    const int* __restrict__ scols, int base, int ncols, int kcnt,
    float* __restrict__ dsim, float* __restrict__ dind, int r, int t)
{
  __syncthreads();
  if (t < ncols){
    int gi = base + t;
    if (gi < kcnt){
      float best = -3.4e38f; int bi = 0;
      #pragma unroll
      for (int g = 0; g < 16; ++g){       // ascending tb == ascending b -> first-index tie-break
        float v = As[t * 16 + g];
        if (v > best){ best = v; bi = (int)Bs[t * 16 + g]; }
      }
      int c = scols[gi];
      dsim[r * NC + c] = best;
      dind[r * NC + c] = (float)bi;
    }
  }
  __syncthreads();
}

__global__ __launch_bounds__(256) void k_gemm_max(
    const float* __restrict__ vis, const float* __restrict__ word,
    float* __restrict__ dind, float* __restrict__ dsim)
{
  __shared__ float As[NB * PIT];      // 3600 floats; also redv (needs <=2048)
  __shared__ float Bs[128 * PIT];     // 4608 floats; also redi
  __shared__ int   scols[NC];
  __shared__ int   sk;
  const int r  = blockIdx.x;
  const int t  = threadIdx.x;
  const int tc = t & 15;
  const int tb = t >> 4;

  if (t == 0) sk = g_cols[0];
  for (int i = t; i < NC; i += 256) scols[i] = g_cols[1 + i];
  // masked columns: S_=0 everywhere -> max 0, argmax 0. Pre-fill all, overwrite active.
  if (t < NC){ dsim[r * NC + t] = 0.f; dind[r * NC + t] = 0.f; }
  __syncthreads();

  const int kcnt = sk;
  const int jcnt = (kcnt + 15) >> 4;
  if (jcnt == 0) return;              // uniform: all columns masked, zeros already written
  const float* abase = vis + (size_t)r * NB * DD;

  const int jc1 = (jcnt > 8) ? 8 : jcnt;
  switch (jc1){
    case 1: gemm_pass<1>(abase, word, scols, As, Bs, t, tc, tb); break;
    case 2: gemm_pass<2>(abase, word, scols, As, Bs, t, tc, tb); break;
    case 3: gemm_pass<3>(abase, word, scols, As, Bs, t, tc, tb); break;
    case 4: gemm_pass<4>(abase, word, scols, As, Bs, t, tc, tb); break;
    case 5: gemm_pass<5>(abase, word, scols, As, Bs, t, tc, tb); break;
    case 6: gemm_pass<6>(abase, word, scols, As, Bs, t, tc, tb); break;
    case 7: gemm_pass<7>(abase, word, scols, As, Bs, t, tc, tb); break;
    default: gemm_pass<8>(abase, word, scols, As, Bs, t, tc, tb); break;
  }
  gemm_epilogue(As, Bs, scols, 0, jc1 * 16, kcnt, dsim, dind, r, t);

  if (jcnt > 8){                      // cold path (needs sum(elen) > 128); keeps VGPR bounded
    const int jc2 = jcnt - 8;         // 1..4
    switch (jc2){
      case 1: gemm_pass<1>(abase, word, scols + 128, As, Bs, t, tc, tb); break;
      case 2: gemm_pass<2>(abase, word, scols + 128, As, Bs, t, tc, tb); break;
      case 3: gemm_pass<3>(abase, word, scols + 128, As, Bs, t, tc, tb); break;
      default: gemm_pass<4>(abase, word, scols + 128, As, Bs, t, tc, tb); break;
    }
    gemm_epilogue(As, Bs, scols, 128, jc2 * 16, kcnt, dsim, dind, r, t);
  }
}

// ---------- K2: IoU ----------
__global__ __launch_bounds__(256) void k_iou(
    const float* __restrict__ boxes, const float* __restrict__ det, float* __restrict__ out)
{
  int idx = blockIdx.x * 256 + threadIdx.x;
  const int total = NA * NS * NB * ML;
  if (idx >= total) return;
  int m = idx % ML; int t2 = idx / ML; int b = t2 % NB; int t3 = t2 / NB;
  const float4 A = *(const float4*)(boxes + (size_t)(t3 * NB + b) * 4);
  int a = t3 / NS;
  const float4 B = *(const float4*)(det + (size_t)(a * ML + m) * 4);
  float iw = fminf(A.z, B.z) - fmaxf(A.x, B.x);
  float ih = fminf(A.w, B.w) - fmaxf(A.y, B.y);
  bool pos = (iw > 0.f) && (ih > 0.f);
  float inter = pos ? iw * ih : 0.f;
  float a1 = (A.z - A.x) * (A.w - A.y);
  float a2 = (B.z - B.x) * (B.w - B.y);
  float den = a1 + a2 - inter;
  out[idx] = pos ? inter / (den > 0.f ? den : 1.f) : 0.f;
}

// ---------- K3a: column-normalize D_sim over s, fold into Sf ----------
__global__ void k_sf(const float* __restrict__ dsim, const int* __restrict__ elen,
                     float* __restrict__ sf)
{
  int a = blockIdx.x, aw = blockIdx.y, s = threadIdx.x;
  float accv = 0.f;
  for (int e = 0; e < NE; ++e){
    int c = aw * NE + e;
    float v = dsim[(a * NS + s) * NC + c];
    float mn, mx; wave_minmax64(v, mn, mx);
    accv += v * (v - mn) / (mx - mn + EPSF);
  }
  float dv = fmaxf((float)elen[aw], 1.f);
  sf[(a * NS + s) * NA + aw] = accv / dv;
}

// ---------- K3b: normalize diagonal sim scores; init accumulators ----------
__global__ void k_simnorm(const float* __restrict__ dsim, float* __restrict__ simn,
                          float* __restrict__ accums)
{
  int a = blockIdx.x, e = blockIdx.y, s = threadIdx.x;
  if (a == 0 && e == 0 && s == 0){ accums[0] = 0.f; accums[1] = 0.f; }
  float v = dsim[(a * NS + s) * NC + (a * NE + e)];
  float mn, mx; wave_minmax64(v, mn, mx);
  simn[(a * NS + s) * NE + e] = (v - mn) / (mx - mn + EPSF);
}

// ---------- K4: vis_loss via ||sum w||^2 identity — parallel-over-s restructure ----------
// phase 1: all 64 row norms computed wave-parallel (no block barriers on the critical path);
// phase 2: W accumulation with coalesced, L2-hot re-reads; s-ascending fmaf chain preserved.
__global__ __launch_bounds__(256) void k_gram(
    const float* __restrict__ vis, const float* __restrict__ dind,
    const float* __restrict__ simn, const int* __restrict__ elen,
    float* __restrict__ accums)
{
  const int a = blockIdx.x, e = blockIdx.y;
  if (e >= elen[a]) return;               // masked (a,e): contributes 0 to sum and count
  __shared__ int   s_mi[NS];
  __shared__ float s_inv[NS];
  __shared__ float s_nw2[NS];
  __shared__ float sred[4];
  const int t = threadIdx.x, lane = t & 63, w = t >> 6;

  if (t < NS) s_mi[t] = (int)dind[(size_t)(a * NS + t) * NC + (a * NE + e)];
  __syncthreads();

  // phase 1: norms — one row per wave-iteration, 4 waves independent
  for (int s = w; s < NS; s += 4){
    const float* row = vis + (size_t)((a * NS + s) * NB + s_mi[s]) * DD;
    float4 v0 = *(const float4*)(row + lane * 8);
    float4 v1 = *(const float4*)(row + lane * 8 + 4);
    float ss = v0.x*v0.x + v0.y*v0.y + v0.z*v0.z + v0.w*v0.w
             + v1.x*v1.x + v1.y*v1.y + v1.z*v1.z + v1.w*v1.w;
    #pragma unroll
    for (int off = 32; off > 0; off >>= 1) ss += __shfl_xor(ss, off);
    if (lane == 0){
      float sn = simn[(size_t)(a * NS + s) * NE + e];
      float d = sqrtf(ss) + EPSF;
      s_inv[s] = sn / d;
      s_nw2[s] = sn * sn * ss / (d * d);
    }
  }
  __syncthreads();

  // phase 2: W = sum_s inv_s * row_s  (same s-ascending order as before)
  float W0 = 0.f, W1 = 0.f;
  #pragma unroll 8
  for (int s = 0; s < NS; ++s){
    const float* row = vis + (size_t)((a * NS + s) * NB + s_mi[s]) * DD;
    float inv = s_inv[s];
    W0 = fmaf(row[t],       inv, W0);
    W1 = fmaf(row[t + 256], inv, W1);
  }
  float w2  = block_sum256(W0 * W0 + W1 * W1, sred);
  float nw2 = block_sum256((t < NS) ? s_nw2[t] : 0.f, sred);
  if (t == 0){
    float part = (float)(NS * (NS - 1)) - w2 + nw2;
    atomicAdd(&accums[0], part);
    atomicAdd(&accums[1], (float)(NS * (NS - 1)));
  }
}

// ---------- K5: Sf margin terms + final loss ----------
__global__ __launch_bounds__(256) void k_final(
    const float* __restrict__ sf, const float* __restrict__ accums, float* __restrict__ out)
{
  __shared__ float sred[4];
  int t = threadIdx.x;
  float sum = 0.f;
  for (int i = t; i < NA * NS * NA; i += 256){
    int b = i & (NA - 1);
    int s = (i >> 4) & (NS - 1);
    int a = i >> 10;
    float v  = sf[i];
    float d1 = sf[(b * NS + s) * NA + b];
    float d2 = sf[(a * NS + s) * NA + a];
    sum += fmaxf(v - d1 + DELTA_F, 0.f) + fmaxf(v - d2 + DELTA_F, 0.f);
    (void)s;
  }
  float tot = block_sum256(sum, sred);
  if (t == 0){
    float frame = tot / (float)(NA * NA * NS);
    float cnt = accums[1];
    float vis_loss = accums[0] / fmaxf(cnt, 1.f);
    out[0] = (frame + vis_loss) * 10.f;
  }
}

// ---------- launch ----------
extern "C" void kernel_launch(void* const* d_in, const int* in_sizes, int n_in,
                              void* d_out, int out_size, void* d_ws, size_t ws_size,
                              hipStream_t stream)
{
  const float* vis   = (const float*)d_in[0];
  const float* word  = (const float*)d_in[1];
  const float* boxes = (const float*)d_in[2];
  const float* det   = (const float*)d_in[3];
  const int*   elen  = (const int*)d_in[4];

  float* out   = (float*)d_out;
  float* dind  = out;                       // 196608 (indices as float)
  float* dsim  = out + NR * NC;             // 196608
  float* mloss = out + 2 * NR * NC;         // 1
  float* dtin  = mloss + 1;                 // 2,048,000

  float* ws     = (float*)d_ws;
  float* sf     = ws;                       // 16*64*16 = 16384
  float* simn   = ws + NA * NS * NA;        // 16*64*12 = 12288
  float* accums = simn + NA * NS * NE;      // 2 floats

  k_cols<<<1, 64, 0, stream>>>(elen);
  k_gemm_max<<<NR, 256, 0, stream>>>(vis, word, dind, dsim);
  k_iou<<<(NA * NS * NB * ML + 255) / 256, 256, 0, stream>>>(boxes, det, dtin);
  k_sf<<<dim3(NA, NA), 64, 0, stream>>>(dsim, elen, sf);
  k_simnorm<<<dim3(NA, NE), 64, 0, stream>>>(dsim, simn, accums);
  k_gram<<<dim3(NA, NE), 256, 0, stream>>>(vis, dind, simn, elen, accums);
  k_final<<<1, 256, 0, stream>>>(sf, accums, mloss);
}

// Round 2
// 521.125 us; speedup vs baseline: 1.3460x; 1.3460x over previous
//
#include <hip/hip_runtime.h>
#include <math.h>

#define NA 16
#define NS 64
#define NB 100
#define NE 12
#define ML 20
#define DD 512
#define NC (NA*NE)   /* 192 */
#define NR (NA*NS)   /* 1024 */
#define EPSF 1e-5f
#define DELTA_F 0.2f
#define IOU_TOTAL (NA*NS*NB*ML)
#define IOU_BLOCKS ((IOU_TOTAL + 255)/256)   /* 8000 */

// ---------- helpers ----------
__device__ inline void wave_minmax64(float v, float& mn, float& mx){
  mn = v; mx = v;
  #pragma unroll
  for (int off = 32; off > 0; off >>= 1){
    mn = fminf(mn, __shfl_xor(mn, off));
    mx = fmaxf(mx, __shfl_xor(mx, off));
  }
}

__device__ inline float block_sum256(float v, float* sred){
  int t = threadIdx.x;
  #pragma unroll
  for (int off = 32; off > 0; off >>= 1) v += __shfl_xor(v, off);
  if ((t & 63) == 0) sred[t >> 6] = v;
  __syncthreads();
  float tot = sred[0] + sred[1] + sred[2] + sred[3];
  __syncthreads();
  return tot;
}

// ---------- gemm pass: round-0 recipe (pitch 33, scalar LDS reads), JC col-groups ----------
template<int JC>
__device__ __forceinline__ void gemm_pass(
    const float* __restrict__ abase, const float* __restrict__ word,
    const int* __restrict__ scols, float* __restrict__ As, float* __restrict__ Bs,
    int t, int tc, int tb)
{
  float acc[7][JC];
  #pragma unroll
  for (int j = 0; j < 7; ++j)
    #pragma unroll
    for (int jc = 0; jc < JC; ++jc) acc[j][jc] = 0.f;

  for (int k0 = 0; k0 < DD; k0 += 32){
    for (int i = t; i < NB * 8; i += 256){
      int b = i >> 3, q = i & 7;
      const float4 v = *(const float4*)(abase + (size_t)b * DD + k0 + q * 4);
      float* d = &As[b * 33 + q * 4];
      d[0] = v.x; d[1] = v.y; d[2] = v.z; d[3] = v.w;
    }
    for (int i = t; i < JC * 16 * 8; i += 256){
      int c = i >> 3, q = i & 7;
      const float4 v = *(const float4*)(word + (size_t)scols[c] * DD + k0 + q * 4);
      float* d = &Bs[c * 33 + q * 4];
      d[0] = v.x; d[1] = v.y; d[2] = v.z; d[3] = v.w;
    }
    __syncthreads();
    #pragma unroll 4
    for (int kk = 0; kk < 32; ++kk){
      float breg[JC], areg[7];
      #pragma unroll
      for (int jc = 0; jc < JC; ++jc) breg[jc] = Bs[(jc * 16 + tc) * 33 + kk];
      #pragma unroll
      for (int j = 0; j < 7; ++j){
        int b = tb * 7 + j; b = (b < NB) ? b : (NB - 1);
        areg[j] = As[b * 33 + kk];
      }
      #pragma unroll
      for (int j = 0; j < 7; ++j)
        #pragma unroll
        for (int jc = 0; jc < JC; ++jc)
          acc[j][jc] = fmaf(areg[j], breg[jc], acc[j][jc]);
    }
    __syncthreads();
  }
  // per-thread max/argmax over this thread's 7 rows (b ascending -> first-index tie-break)
  #pragma unroll
  for (int jc = 0; jc < JC; ++jc){
    int ci = jc * 16 + tc;
    float best = -3.4e38f; int bi = 0;
    #pragma unroll
    for (int j = 0; j < 7; ++j){
      int b = tb * 7 + j;
      if (b < NB){ float v = acc[j][jc]; if (v > best){ best = v; bi = b; } }
    }
    As[ci * 16 + tb] = best;
    Bs[ci * 16 + tb] = (float)bi;
  }
}

__device__ __forceinline__ void gemm_epilogue(
    const float* __restrict__ As, const float* __restrict__ Bs,
    const int* __restrict__ scols, int base, int ncols, int kcnt,
    float* __restrict__ dsim, float* __restrict__ dind, int r, int t)
{
  __syncthreads();
  if (t < ncols){
    int gi = base + t;
    if (gi < kcnt){
      float best = -3.4e38f; int bi = 0;
      #pragma unroll
      for (int g = 0; g < 16; ++g){       // ascending tb == ascending b -> first-index tie-break
        float v = As[t * 16 + g];
        if (v > best){ best = v; bi = (int)Bs[t * 16 + g]; }
      }
      int c = scols[gi];
      dsim[r * NC + c] = best;
      dind[r * NC + c] = (float)bi;
    }
  }
  __syncthreads();
}

// ---------- K1: fused {active-col GEMM+max/argmax} + {IoU tail blocks} ----------
__global__ __launch_bounds__(256) void k_main(
    const float* __restrict__ vis, const float* __restrict__ word,
    const int* __restrict__ elen, const float* __restrict__ boxes,
    const float* __restrict__ det,
    float* __restrict__ dind, float* __restrict__ dsim, float* __restrict__ dtin)
{
  const int t = threadIdx.x;

  if (blockIdx.x >= NR){
    // ---- IoU path (memory-bound, overlaps with gemm blocks) ----
    int idx = (int)(blockIdx.x - NR) * 256 + t;
    if (idx < IOU_TOTAL){
      int m = idx % ML; int t2 = idx / ML; int b = t2 % NB; int t3 = t2 / NB;
      const float4 A = *(const float4*)(boxes + (size_t)(t3 * NB + b) * 4);
      int a = t3 / NS;
      const float4 B = *(const float4*)(det + (size_t)(a * ML + m) * 4);
      float iw = fminf(A.z, B.z) - fmaxf(A.x, B.x);
      float ih = fminf(A.w, B.w) - fmaxf(A.y, B.y);
      bool pos = (iw > 0.f) && (ih > 0.f);
      float inter = pos ? iw * ih : 0.f;
      float a1 = (A.z - A.x) * (A.w - A.y);
      float a2 = (B.z - B.x) * (B.w - B.y);
      float den = a1 + a2 - inter;
      dtin[idx] = pos ? inter / (den > 0.f ? den : 1.f) : 0.f;
    }
    return;
  }

  // ---- GEMM path ----
  __shared__ float As[NB * 33];       // 3300 floats; aliased as redv (needs <=2048)
  __shared__ float Bs[128 * 33];      // 4224 floats; aliased as redi
  __shared__ int   scols[NC];
  __shared__ int   s_el[NA];
  __shared__ int   s_cnt;
  const int r  = blockIdx.x;
  const int tc = t & 15;
  const int tb = t >> 4;

  // per-block parallel active-column list (elen is 64B, L2-hot)
  if (t < NA){ int L = elen[t]; L = L < 0 ? 0 : (L > NE ? NE : L); s_el[t] = L; }
  // masked columns: S_=0 everywhere -> max 0, argmax 0. Pre-fill all, overwrite active.
  if (t < NC){ dsim[r * NC + t] = 0.f; dind[r * NC + t] = 0.f; }
  __syncthreads();
  if (t < NC){
    int aw = t / NE, e = t - aw * NE;
    int base = 0;
    #pragma unroll
    for (int i = 0; i < NA; ++i) base += (i < aw) ? s_el[i] : 0;
    if (e < s_el[aw]) scols[base + e] = t;
  }
  if (t == 0){
    int n = 0;
    #pragma unroll
    for (int i = 0; i < NA; ++i) n += s_el[i];
    s_cnt = n;
  }
  __syncthreads();
  const int kcnt = s_cnt;
  if (t < NC && t >= kcnt) scols[t] = (kcnt > 0) ? scols[kcnt - 1] : 0;  // pad tail
  __syncthreads();

  const int jcnt = (kcnt + 15) >> 4;
  if (jcnt == 0) return;              // uniform: all columns masked, zeros already written
  const float* abase = vis + (size_t)r * NB * DD;

  const int jc1 = (jcnt > 8) ? 8 : jcnt;
  switch (jc1){
    case 1: gemm_pass<1>(abase, word, scols, As, Bs, t, tc, tb); break;
    case 2: gemm_pass<2>(abase, word, scols, As, Bs, t, tc, tb); break;
    case 3: gemm_pass<3>(abase, word, scols, As, Bs, t, tc, tb); break;
    case 4: gemm_pass<4>(abase, word, scols, As, Bs, t, tc, tb); break;
    case 5: gemm_pass<5>(abase, word, scols, As, Bs, t, tc, tb); break;
    case 6: gemm_pass<6>(abase, word, scols, As, Bs, t, tc, tb); break;
    case 7: gemm_pass<7>(abase, word, scols, As, Bs, t, tc, tb); break;
    default: gemm_pass<8>(abase, word, scols, As, Bs, t, tc, tb); break;
  }
  gemm_epilogue(As, Bs, scols, 0, jc1 * 16, kcnt, dsim, dind, r, t);

  if (jcnt > 8){                      // cold path (needs sum(elen) > 128, P~0.2%)
    const int jc2 = jcnt - 8;         // 1..4
    switch (jc2){
      case 1: gemm_pass<1>(abase, word, scols + 128, As, Bs, t, tc, tb); break;
      case 2: gemm_pass<2>(abase, word, scols + 128, As, Bs, t, tc, tb); break;
      case 3: gemm_pass<3>(abase, word, scols + 128, As, Bs, t, tc, tb); break;
      default: gemm_pass<4>(abase, word, scols + 128, As, Bs, t, tc, tb); break;
    }
    gemm_epilogue(As, Bs, scols, 128, jc2 * 16, kcnt, dsim, dind, r, t);
  }
}

// ---------- K2: column-normalize D_sim over s -> Sf; diagonal block also emits simn ----------
// grid (NA, NA), block 64. Block (a,a) computes exactly the columns simnorm needs.
__global__ void k_sfsim(const float* __restrict__ dsim, const int* __restrict__ elen,
                        float* __restrict__ sf, float* __restrict__ simn,
                        float* __restrict__ accums)
{
  int a = blockIdx.x, aw = blockIdx.y, s = threadIdx.x;
  if (a == 0 && aw == 0 && s == 0){ accums[0] = 0.f; accums[1] = 0.f; }
  const bool diag = (aw == a);
  float accv = 0.f;
  for (int e = 0; e < NE; ++e){
    int c = aw * NE + e;
    float v = dsim[(a * NS + s) * NC + c];
    float mn, mx; wave_minmax64(v, mn, mx);
    float nv = (v - mn) / (mx - mn + EPSF);
    accv += v * nv;
    if (diag) simn[(a * NS + s) * NE + e] = nv;
  }
  float dv = fmaxf((float)elen[aw], 1.f);
  sf[(a * NS + s) * NA + aw] = accv / dv;
}

// ---------- K3: vis_loss via ||sum w||^2 identity — parallel-over-s ----------
__global__ __launch_bounds__(256) void k_gram(
    const float* __restrict__ vis, const float* __restrict__ dind,
    const float* __restrict__ simn, const int* __restrict__ elen,
    float* __restrict__ accums)
{
  const int a = blockIdx.x, e = blockIdx.y;
  if (e >= elen[a]) return;               // masked (a,e): contributes 0 to sum and count
  __shared__ int   s_mi[NS];
  __shared__ float s_inv[NS];
  __shared__ float s_nw2[NS];
  __shared__ float sred[4];
  const int t = threadIdx.x, lane = t & 63, w = t >> 6;

  if (t < NS) s_mi[t] = (int)dind[(size_t)(a * NS + t) * NC + (a * NE + e)];
  __syncthreads();

  // phase 1: all 64 row norms, wave-parallel
  for (int s = w; s < NS; s += 4){
    const float* row = vis + (size_t)((a * NS + s) * NB + s_mi[s]) * DD;
    float4 v0 = *(const float4*)(row + lane * 8);
    float4 v1 = *(const float4*)(row + lane * 8 + 4);
    float ss = v0.x*v0.x + v0.y*v0.y + v0.z*v0.z + v0.w*v0.w
             + v1.x*v1.x + v1.y*v1.y + v1.z*v1.z + v1.w*v1.w;
    #pragma unroll
    for (int off = 32; off > 0; off >>= 1) ss += __shfl_xor(ss, off);
    if (lane == 0){
      float sn = simn[(size_t)(a * NS + s) * NE + e];
      float d = sqrtf(ss) + EPSF;
      s_inv[s] = sn / d;
      s_nw2[s] = sn * sn * ss / (d * d);
    }
  }
  __syncthreads();

  // phase 2: W = sum_s inv_s * row_s (s-ascending chain preserved; rows L2-hot)
  float W0 = 0.f, W1 = 0.f;
  #pragma unroll 8
  for (int s = 0; s < NS; ++s){
    const float* row = vis + (size_t)((a * NS + s) * NB + s_mi[s]) * DD;
    float inv = s_inv[s];
    W0 = fmaf(row[t],       inv, W0);
    W1 = fmaf(row[t + 256], inv, W1);
  }
  float w2  = block_sum256(W0 * W0 + W1 * W1, sred);
  float nw2 = block_sum256((t < NS) ? s_nw2[t] : 0.f, sred);
  if (t == 0){
    float part = (float)(NS * (NS - 1)) - w2 + nw2;
    atomicAdd(&accums[0], part);
    atomicAdd(&accums[1], (float)(NS * (NS - 1)));
  }
}

// ---------- K4: Sf margin terms + final loss ----------
__global__ __launch_bounds__(256) void k_final(
    const float* __restrict__ sf, const float* __restrict__ accums, float* __restrict__ out)
{
  __shared__ float sred[4];
  int t = threadIdx.x;
  float sum = 0.f;
  for (int i = t; i < NA * NS * NA; i += 256){
    int b = i & (NA - 1);
    int s = (i >> 4) & (NS - 1);
    int a = i >> 10;
    float v  = sf[i];
    float d1 = sf[(b * NS + s) * NA + b];
    float d2 = sf[(a * NS + s) * NA + a];
    sum += fmaxf(v - d1 + DELTA_F, 0.f) + fmaxf(v - d2 + DELTA_F, 0.f);
  }
  float tot = block_sum256(sum, sred);
  if (t == 0){
    float frame = tot / (float)(NA * NA * NS);
    float cnt = accums[1];
    float vis_loss = accums[0] / fmaxf(cnt, 1.f);
    out[0] = (frame + vis_loss) * 10.f;
  }
}

// ---------- launch ----------
extern "C" void kernel_launch(void* const* d_in, const int* in_sizes, int n_in,
                              void* d_out, int out_size, void* d_ws, size_t ws_size,
                              hipStream_t stream)
{
  const float* vis   = (const float*)d_in[0];
  const float* word  = (const float*)d_in[1];
  const float* boxes = (const float*)d_in[2];
  const float* det   = (const float*)d_in[3];
  const int*   elen  = (const int*)d_in[4];

  float* out   = (float*)d_out;
  float* dind  = out;                       // 196608 (indices as float)
  float* dsim  = out + NR * NC;             // 196608
  float* mloss = out + 2 * NR * NC;         // 1
  float* dtin  = mloss + 1;                 // 2,048,000

  float* ws     = (float*)d_ws;
  float* sf     = ws;                       // 16*64*16 = 16384
  float* simn   = ws + NA * NS * NA;        // 16*64*12 = 12288
  float* accums = simn + NA * NS * NE;      // 2 floats

  k_main<<<NR + IOU_BLOCKS, 256, 0, stream>>>(vis, word, elen, boxes, det, dind, dsim, dtin);
  k_sfsim<<<dim3(NA, NA), 64, 0, stream>>>(dsim, elen, sf, simn, accums);
  k_gram<<<dim3(NA, NE), 256, 0, stream>>>(vis, dind, simn, elen, accums);
  k_final<<<1, 256, 0, stream>>>(sf, accums, mloss);
}

// Round 3
// 505.687 us; speedup vs baseline: 1.3871x; 1.0305x over previous
//
#include <hip/hip_runtime.h>
#include <math.h>

#define NA 16
#define NS 64
#define NB 100
#define NE 12
#define ML 20
#define DD 512
#define NC (NA*NE)   /* 192 */
#define NR (NA*NS)   /* 1024 */
#define EPSF 1e-5f
#define DELTA_F 0.2f
#define IOU_TOTAL (NA*NS*NB*ML)
#define IOU_BLOCKS ((IOU_TOTAL + 255)/256)   /* 8000 */
#define PIT 34       /* even pitch: 8B-aligned ds_read_b64; banks 2*tc+kk conflict-free */
#define MID_BLOCKS (NA*(NE+1))               /* 208 */

// ---------- helpers ----------
__device__ inline void wave_minmax64(float v, float& mn, float& mx){
  mn = v; mx = v;
  #pragma unroll
  for (int off = 32; off > 0; off >>= 1){
    mn = fminf(mn, __shfl_xor(mn, off));
    mx = fmaxf(mx, __shfl_xor(mx, off));
  }
}

__device__ inline float block_sum256(float v, float* sred){
  int t = threadIdx.x;
  #pragma unroll
  for (int off = 32; off > 0; off >>= 1) v += __shfl_xor(v, off);
  if ((t & 63) == 0) sred[t >> 6] = v;
  __syncthreads();
  float tot = sred[0] + sred[1] + sred[2] + sred[3];
  __syncthreads();
  return tot;
}

// ---------- gemm pass: pitch-34 tiles, ds_read_b64 kk-pairs, JC col-groups ----------
// fmaf chain per accumulator is kk-ascending (x then y) -> bit-identical to b32 version.
template<int JC>
__device__ __forceinline__ void gemm_pass(
    const float* __restrict__ abase, const float* __restrict__ word,
    const int* __restrict__ scols, float* __restrict__ As, float* __restrict__ Bs,
    int t, int tc, int tb)
{
  float acc[7][JC];
  #pragma unroll
  for (int j = 0; j < 7; ++j)
    #pragma unroll
    for (int jc = 0; jc < JC; ++jc) acc[j][jc] = 0.f;

  for (int k0 = 0; k0 < DD; k0 += 32){
    for (int i = t; i < NB * 8; i += 256){
      int b = i >> 3, q = i & 7;
      const float4 v = *(const float4*)(abase + (size_t)b * DD + k0 + q * 4);
      float* d = &As[b * PIT + q * 4];
      *(float2*)d       = make_float2(v.x, v.y);
      *(float2*)(d + 2) = make_float2(v.z, v.w);
    }
    for (int i = t; i < JC * 16 * 8; i += 256){
      int c = i >> 3, q = i & 7;
      const float4 v = *(const float4*)(word + (size_t)scols[c] * DD + k0 + q * 4);
      float* d = &Bs[c * PIT + q * 4];
      *(float2*)d       = make_float2(v.x, v.y);
      *(float2*)(d + 2) = make_float2(v.z, v.w);
    }
    __syncthreads();
    #pragma unroll 4
    for (int kk = 0; kk < 32; kk += 2){
      float2 breg[JC], areg[7];
      #pragma unroll
      for (int jc = 0; jc < JC; ++jc)
        breg[jc] = *(const float2*)&Bs[(jc * 16 + tc) * PIT + kk];
      #pragma unroll
      for (int j = 0; j < 7; ++j){
        int b = tb * 7 + j; b = (b < NB) ? b : (NB - 1);
        areg[j] = *(const float2*)&As[b * PIT + kk];
      }
      #pragma unroll
      for (int j = 0; j < 7; ++j)
        #pragma unroll
        for (int jc = 0; jc < JC; ++jc){
          float s0 = acc[j][jc];
          s0 = fmaf(areg[j].x, breg[jc].x, s0);
          s0 = fmaf(areg[j].y, breg[jc].y, s0);
          acc[j][jc] = s0;
        }
    }
    __syncthreads();
  }
  // per-thread max/argmax over this thread's 7 rows (b ascending -> first-index tie-break)
  #pragma unroll
  for (int jc = 0; jc < JC; ++jc){
    int ci = jc * 16 + tc;
    float best = -3.4e38f; int bi = 0;
    #pragma unroll
    for (int j = 0; j < 7; ++j){
      int b = tb * 7 + j;
      if (b < NB){ float v = acc[j][jc]; if (v > best){ best = v; bi = b; } }
    }
    As[ci * 16 + tb] = best;
    Bs[ci * 16 + tb] = (float)bi;
  }
}

__device__ __forceinline__ void gemm_epilogue(
    const float* __restrict__ As, const float* __restrict__ Bs,
    const int* __restrict__ scols, int base, int ncols, int kcnt,
    float* __restrict__ dsim, float* __restrict__ dind, int r, int t)
{
  __syncthreads();
  if (t < ncols){
    int gi = base + t;
    if (gi < kcnt){
      float best = -3.4e38f; int bi = 0;
      #pragma unroll
      for (int g = 0; g < 16; ++g){       // ascending tb == ascending b -> first-index tie-break
        float v = As[t * 16 + g];
        if (v > best){ best = v; bi = (int)Bs[t * 16 + g]; }
      }
      int c = scols[gi];
      dsim[r * NC + c] = best;
      dind[r * NC + c] = (float)bi;
    }
  }
  __syncthreads();
}

// ---------- K1: fused {active-col GEMM+max/argmax} + {IoU tail blocks} ----------
__global__ __launch_bounds__(256) void k_main(
    const float* __restrict__ vis, const float* __restrict__ word,
    const int* __restrict__ elen, const float* __restrict__ boxes,
    const float* __restrict__ det,
    float* __restrict__ dind, float* __restrict__ dsim, float* __restrict__ dtin,
    float* __restrict__ accums, unsigned int* __restrict__ done)
{
  const int t = threadIdx.x;

  if (blockIdx.x >= NR){
    // ---- IoU path (memory-bound, overlaps with gemm blocks) ----
    int idx = (int)(blockIdx.x - NR) * 256 + t;
    if (idx < IOU_TOTAL){
      int m = idx % ML; int t2 = idx / ML; int b = t2 % NB; int t3 = t2 / NB;
      const float4 A = *(const float4*)(boxes + (size_t)(t3 * NB + b) * 4);
      int a = t3 / NS;
      const float4 B = *(const float4*)(det + (size_t)(a * ML + m) * 4);
      float iw = fminf(A.z, B.z) - fmaxf(A.x, B.x);
      float ih = fminf(A.w, B.w) - fmaxf(A.y, B.y);
      bool pos = (iw > 0.f) && (ih > 0.f);
      float inter = pos ? iw * ih : 0.f;
      float a1 = (A.z - A.x) * (A.w - A.y);
      float a2 = (B.z - B.x) * (B.w - B.y);
      float den = a1 + a2 - inter;
      dtin[idx] = pos ? inter / (den > 0.f ? den : 1.f) : 0.f;
    }
    return;
  }

  // ---- GEMM path ----
  __shared__ float As[NB * PIT];      // 3400 floats; aliased as redv (needs <=2048)
  __shared__ float Bs[128 * PIT];     // 4352 floats; aliased as redi
  __shared__ int   scols[NC];
  __shared__ int   s_el[NA];
  __shared__ int   s_cnt;
  const int r  = blockIdx.x;
  const int tc = t & 15;
  const int tb = t >> 4;

  if (r == 0 && t == 0){ accums[0] = 0.f; accums[1] = 0.f; done[0] = 0u; }

  // per-block parallel active-column list (elen is 64B, L2-hot)
  if (t < NA){ int L = elen[t]; L = L < 0 ? 0 : (L > NE ? NE : L); s_el[t] = L; }
  // masked columns: S_=0 everywhere -> max 0, argmax 0. Pre-fill all, overwrite active.
  if (t < NC){ dsim[r * NC + t] = 0.f; dind[r * NC + t] = 0.f; }
  __syncthreads();
  if (t < NC){
    int aw = t / NE, e = t - aw * NE;
    int base = 0;
    #pragma unroll
    for (int i = 0; i < NA; ++i) base += (i < aw) ? s_el[i] : 0;
    if (e < s_el[aw]) scols[base + e] = t;
  }
  if (t == 0){
    int n = 0;
    #pragma unroll
    for (int i = 0; i < NA; ++i) n += s_el[i];
    s_cnt = n;
  }
  __syncthreads();
  const int kcnt = s_cnt;
  if (t < NC && t >= kcnt) scols[t] = (kcnt > 0) ? scols[kcnt - 1] : 0;  // pad tail
  __syncthreads();

  const int jcnt = (kcnt + 15) >> 4;
  if (jcnt == 0) return;              // uniform: all columns masked, zeros already written
  const float* abase = vis + (size_t)r * NB * DD;

  const int jc1 = (jcnt > 8) ? 8 : jcnt;
  switch (jc1){
    case 1: gemm_pass<1>(abase, word, scols, As, Bs, t, tc, tb); break;
    case 2: gemm_pass<2>(abase, word, scols, As, Bs, t, tc, tb); break;
    case 3: gemm_pass<3>(abase, word, scols, As, Bs, t, tc, tb); break;
    case 4: gemm_pass<4>(abase, word, scols, As, Bs, t, tc, tb); break;
    case 5: gemm_pass<5>(abase, word, scols, As, Bs, t, tc, tb); break;
    case 6: gemm_pass<6>(abase, word, scols, As, Bs, t, tc, tb); break;
    case 7: gemm_pass<7>(abase, word, scols, As, Bs, t, tc, tb); break;
    default: gemm_pass<8>(abase, word, scols, As, Bs, t, tc, tb); break;
  }
  gemm_epilogue(As, Bs, scols, 0, jc1 * 16, kcnt, dsim, dind, r, t);

  if (jcnt > 8){                      // cold path (needs sum(elen) > 128)
    const int jc2 = jcnt - 8;         // 1..4
    switch (jc2){
      case 1: gemm_pass<1>(abase, word, scols + 128, As, Bs, t, tc, tb); break;
      case 2: gemm_pass<2>(abase, word, scols + 128, As, Bs, t, tc, tb); break;
      case 3: gemm_pass<3>(abase, word, scols + 128, As, Bs, t, tc, tb); break;
      default: gemm_pass<4>(abase, word, scols + 128, As, Bs, t, tc, tb); break;
    }
    gemm_epilogue(As, Bs, scols, 128, jc2 * 16, kcnt, dsim, dind, r, t);
  }
}

// ---------- K2: fused {Sf columns} + {vis_loss blocks} + last-block final reduction ----------
// grid (NA, NE+1): y<NE -> gram role for (a,e) (computes own simn in-block);
//                  y==NE -> sf role for a (4 waves x 4 aw each).
__global__ __launch_bounds__(256) void k_mid(
    const float* __restrict__ vis, const float* __restrict__ dind,
    const float* __restrict__ dsim, const int* __restrict__ elen,
    float* __restrict__ sf, float* __restrict__ accums,
    unsigned int* __restrict__ done, float* __restrict__ out)
{
  const int a = blockIdx.x, y = blockIdx.y;
  const int t = threadIdx.x, lane = t & 63, w = t >> 6;
  __shared__ float sred[4];
  __shared__ int   s_mi[NS];
  __shared__ float s_inv[NS];
  __shared__ float s_nw2[NS];
  __shared__ float s_sn[NS];
  __shared__ int   s_last;

  if (y == NE){
    // ---- sf role: column-normalize D_sim over s, fold into Sf. wave w -> aw = w,w+4,w+8,w+12
    for (int aw = w; aw < NA; aw += 4){
      float accv = 0.f;
      for (int e = 0; e < NE; ++e){
        int c = aw * NE + e;
        float v = dsim[(a * NS + lane) * NC + c];
        float mn, mx; wave_minmax64(v, mn, mx);
        accv += v * (v - mn) / (mx - mn + EPSF);
      }
      float dv = fmaxf((float)elen[aw], 1.f);
      sf[(a * NS + lane) * NA + aw] = accv / dv;
    }
  } else {
    const int e = y;
    if (e < elen[a]){
      // ---- gram role: vis_loss via ||sum w||^2 identity; simn computed in-block
      if (w == 0){
        float v = dsim[(a * NS + lane) * NC + (a * NE + e)];
        float mn, mx; wave_minmax64(v, mn, mx);    // same 64-lane chain as old k_simnorm
        s_sn[lane] = (v - mn) / (mx - mn + EPSF);
      }
      if (t < NS) s_mi[t] = (int)dind[(size_t)(a * NS + t) * NC + (a * NE + e)];
      __syncthreads();

      // phase 1: all 64 row norms, wave-parallel
      for (int s = w; s < NS; s += 4){
        const float* row = vis + (size_t)((a * NS + s) * NB + s_mi[s]) * DD;
        float4 v0 = *(const float4*)(row + lane * 8);
        float4 v1 = *(const float4*)(row + lane * 8 + 4);
        float ss = v0.x*v0.x + v0.y*v0.y + v0.z*v0.z + v0.w*v0.w
                 + v1.x*v1.x + v1.y*v1.y + v1.z*v1.z + v1.w*v1.w;
        #pragma unroll
        for (int off = 32; off > 0; off >>= 1) ss += __shfl_xor(ss, off);
        if (lane == 0){
          float sn = s_sn[s];
          float d = sqrtf(ss) + EPSF;
          s_inv[s] = sn / d;
          s_nw2[s] = sn * sn * ss / (d * d);
        }
      }
      __syncthreads();

      // phase 2: W = sum_s inv_s * row_s (s-ascending chain preserved; rows L2-hot)
      float W0 = 0.f, W1 = 0.f;
      #pragma unroll 8
      for (int s = 0; s < NS; ++s){
        const float* row = vis + (size_t)((a * NS + s) * NB + s_mi[s]) * DD;
        float inv = s_inv[s];
        W0 = fmaf(row[t],       inv, W0);
        W1 = fmaf(row[t + 256], inv, W1);
      }
      float w2  = block_sum256(W0 * W0 + W1 * W1, sred);
      float nw2 = block_sum256((t < NS) ? s_nw2[t] : 0.f, sred);
      if (t == 0){
        float part = (float)(NS * (NS - 1)) - w2 + nw2;
        atomicAdd(&accums[0], part);
        atomicAdd(&accums[1], (float)(NS * (NS - 1)));
      }
    }
  }

  // ---- completion: last finishing block runs the final reduction ----
  __syncthreads();                       // all waves' global writes drained at barrier
  if (t == 0){
    __threadfence();                     // release our sf/accums writes
    unsigned int old = atomicAdd(done, 1u);
    s_last = (old == (unsigned int)(MID_BLOCKS - 1)) ? 1 : 0;
  }
  __syncthreads();
  if (s_last){
    __threadfence();                     // acquire all other blocks' writes
    float sum = 0.f;
    for (int i = t; i < NA * NS * NA; i += 256){
      int b = i & (NA - 1);
      int a2 = i >> 10;
      float v  = sf[i];
      int s2 = (i >> 4) & (NS - 1);
      float d1 = sf[(b * NS + s2) * NA + b];
      float d2 = sf[(a2 * NS + s2) * NA + a2];
      sum += fmaxf(v - d1 + DELTA_F, 0.f) + fmaxf(v - d2 + DELTA_F, 0.f);
    }
    float tot = block_sum256(sum, sred);
    if (t == 0){
      float frame = tot / (float)(NA * NA * NS);
      float cnt = accums[1];
      float vis_loss = accums[0] / fmaxf(cnt, 1.f);
      out[0] = (frame + vis_loss) * 10.f;
    }
  }
}

// ---------- launch ----------
extern "C" void kernel_launch(void* const* d_in, const int* in_sizes, int n_in,
                              void* d_out, int out_size, void* d_ws, size_t ws_size,
                              hipStream_t stream)
{
  const float* vis   = (const float*)d_in[0];
  const float* word  = (const float*)d_in[1];
  const float* boxes = (const float*)d_in[2];
  const float* det   = (const float*)d_in[3];
  const int*   elen  = (const int*)d_in[4];

  float* out   = (float*)d_out;
  float* dind  = out;                       // 196608 (indices as float)
  float* dsim  = out + NR * NC;             // 196608
  float* mloss = out + 2 * NR * NC;         // 1
  float* dtin  = mloss + 1;                 // 2,048,000

  float* ws     = (float*)d_ws;
  float* sf     = ws;                       // 16*64*16 = 16384
  float* accums = ws + NA * NS * NA;        // 2 floats
  unsigned int* done = (unsigned int*)(accums + 2);

  k_main<<<NR + IOU_BLOCKS, 256, 0, stream>>>(vis, word, elen, boxes, det,
                                              dind, dsim, dtin, accums, done);
  k_mid<<<dim3(NA, NE + 1), 256, 0, stream>>>(vis, dind, dsim, elen,
                                              sf, accums, done, mloss);
}